// Round 8
// baseline (101.017 us; speedup 1.0000x reference)
//
#include <hip/hip_runtime.h>
#include <hip/hip_bf16.h>

// AEV for M=32 molecules, A=48 atoms, S=4 species.
// Output [M, A, 384]: [0:64] radial = species*16+shfR; [64:384] angular =
// pair_species_idx*32 + shfA*8 + shfZ.
//
// One 256-thread (4-wave) block per (molecule, center); all 1536 blocks
// co-resident. Wave 0 builds cutoff-compacted neighbor lists (ballot+popc).
// Radial: folded single-exp2 per (neighbor, shell), strided across waves.
// Angular TRANSPOSED: lane = pair (p = 4*lane+w, multi-pass guard), serial
// fully-unrolled loop over the 32 (shfA, shfZ) features. No shfl, no row
// select: each lane atomicAdds its term into a per-wave LDS partial
// apart[w][qp*33 + a*8 + z] (rows padded to 33 -> distinct species-pair rows
// hit distinct banks; same-row lanes serialize ~4-way, cheap). f1 (the
// ((1+cos(θ-ShfZ))/2)^ζ chain) hoisted over the 4 ShfA values.
// Pair decode p->(j,k) via closed-form quadratic + integer correction.
// Partials tree-reduced after one final barrier.
//
// Dtype probed at runtime (ShfR[0] as f32 == 0.9 <=> f32 inputs; confirmed f32).

#define NA 48
#define RCR_F 5.2f
#define RCA_F 3.5f
#define PI_F 3.14159265358979f
#define LOG2E_F 1.44269504088896f
#define RADLEN 64
#define AEVLEN 384

struct Smem {
    float sx[NA], sy[NA], sz[NA];
    int   ssp[NA];
    float ra[NA]; unsigned rbu[NA];                                // radial folded
    float ad[NA], avx[NA], avy[NA], avz[NA], afc[NA]; int asp[NA]; // d<=RCA list
    int   nR, nAn;
    float rpart[4][64];    // per-wave radial partials
    float apart[4][330];   // per-wave angular partials, 10 rows x 33 (padded)
};

template <typename T> __device__ __forceinline__ float toF(const T* p, int i);
template <> __device__ __forceinline__ float toF<float>(const float* p, int i) { return p[i]; }
template <> __device__ __forceinline__ float toF<__hip_bfloat16>(const __hip_bfloat16* p, int i) { return __bfloat162float(p[i]); }

template <typename T> __device__ __forceinline__ void stF(T* p, size_t i, float v);
template <> __device__ __forceinline__ void stF<float>(float* p, size_t i, float v) { p[i] = v; }
template <> __device__ __forceinline__ void stF<__hip_bfloat16>(__hip_bfloat16* p, size_t i, float v) { p[i] = __float2bfloat16(v); }

__device__ __forceinline__ int triu_idx(int a, int b) {
    int lo = a < b ? a : b;
    int hi = a < b ? b : a;
    return lo * 4 - (lo * (lo - 1)) / 2 + (hi - lo);  // 4x4 upper-tri, 0..9
}

template <typename T>
__device__ void aev_body(Smem& sm,
    const T* __restrict__ coords, const T* __restrict__ etaR_p,
    const T* __restrict__ shfR_p, const T* __restrict__ etaA_p,
    const T* __restrict__ zeta_p, const T* __restrict__ shfA_p,
    const T* __restrict__ shfZ_p, const int* __restrict__ species,
    T* __restrict__ out)
{
    const int tid  = threadIdx.x;   // 0..255
    const int lane = tid & 63;
    const int w    = tid >> 6;      // wave id 0..3
    const int bid  = blockIdx.x;    // 0..1535
    const int m  = bid / NA;
    const int ci = bid % NA;

    const float etaR = toF(etaR_p, 0);
    const float etaA = toF(etaA_p, 0);
    const float zeta = toF(zeta_p, 0);
    const float kR   = etaR * LOG2E_F;
    const float k2   = etaA * LOG2E_F;

    if (tid < NA) {
        int g = m * NA + tid;
        sm.sx[tid]  = toF(coords, 3 * g + 0);
        sm.sy[tid]  = toF(coords, 3 * g + 1);
        sm.sz[tid]  = toF(coords, 3 * g + 2);
        sm.ssp[tid] = species[g];
    }
    // zero the per-wave angular partials (own wave -> no barrier needed)
    for (int i = lane; i < 330; i += 64) sm.apart[w][i] = 0.f;
    __syncthreads();

    if (w == 0) {
        const float cx = sm.sx[ci], cy = sm.sy[ci], cz = sm.sz[ci];
        float dx = 0.f, dy = 0.f, dz = 0.f, d = 1e30f;
        if (lane < NA && lane != ci) {
            dx = sm.sx[lane] - cx; dy = sm.sy[lane] - cy; dz = sm.sz[lane] - cz;
            d = sqrtf(dx * dx + dy * dy + dz * dz);
        }
        unsigned long long mR = __ballot(d <= RCR_F);
        unsigned long long mA = __ballot(d <= RCA_F);
        unsigned long long lanebit = 1ull << lane;
        unsigned long long below = lanebit - 1ull;
        if (mR & lanebit) {
            int s = __popcll(mR & below);
            float fcR = 0.5f * __cosf(d * (PI_F / RCR_F)) + 0.5f;
            // 0.25*exp(-etaR*(d-s)^2)*fc = exp2(ra*s + rb - kR*s^2)
            float rb = fmaxf(__log2f(0.25f * fcR) - kR * d * d, -8.0e4f);
            sm.ra[s]  = 2.f * kR * d;
            sm.rbu[s] = (__float_as_uint(rb) & ~3u) | (unsigned)sm.ssp[lane];
        }
        if (mA & lanebit) {
            int s = __popcll(mA & below);
            sm.ad[s]  = d;
            sm.avx[s] = dx; sm.avy[s] = dy; sm.avz[s] = dz;
            sm.afc[s] = 0.5f * __cosf(d * (PI_F / RCA_F)) + 0.5f;
            sm.asp[s] = sm.ssp[lane];
        }
        if (lane == 0) { sm.nR = (int)__popcll(mR); sm.nAn = (int)__popcll(mA); }
    }
    __syncthreads();

    const int nR  = sm.nR;
    const int nAn = sm.nAn;

    const float myShfR = toF(shfR_p, lane & 15);
    const int   mySp   = lane >> 4;
    const float myRc   = kR * myShfR * myShfR;
    const bool  z32    = (zeta == 32.f);

    // ---- radial partial: wave w handles neighbors w, w+4, ... ----
    float racc = 0.f;
    for (int i = w; i < nR; i += 4) {
        unsigned ru = sm.rbu[i];
        float arg = __builtin_fmaf(sm.ra[i], myShfR, __uint_as_float(ru)) - myRc;
        float t = __builtin_amdgcn_exp2f(arg);
        racc += ((int)(ru & 3u) == mySp) ? t : 0.f;
    }
    sm.rpart[w][lane] = racc;

    // ---- angular, transposed: lane = pair, serial loop = 32 features ----
    // wave-uniform feature constants
    float czv[8], szv[8], shfa[4], lca[4];
    #pragma unroll
    for (int z = 0; z < 8; z++) {
        float s = toF(shfZ_p, z);
        czv[z] = __cosf(s);
        szv[z] = __sinf(s);
    }
    #pragma unroll
    for (int a = 0; a < 4; a++) {
        shfa[a] = toF(shfA_p, a);
        lca[a]  = k2 * shfa[a] * shfa[a];
    }

    const int np = nAn * (nAn - 1) / 2;
    for (int p = 4 * lane + w; p < np; p += 256) {
        // decode p -> (j,k), j<k: row start T(j) = j*(2n-1-j)/2
        const int b = 2 * nAn - 1;
        float s = sqrtf((float)(b * b - 8 * p));
        int j = (int)(((float)b - s) * 0.5f);
        if ((j + 1) * (b - 1 - j) <= 2 * p) j++;   // T(j+1) <= p
        if (j * (b - j) > 2 * p) j--;              // T(j)   >  p
        int k = p - ((j * (b - j)) >> 1) + j + 1;

        float d1 = sm.ad[j], d2 = sm.ad[k];
        float dot = sm.avx[j] * sm.avx[k] + sm.avy[j] * sm.avy[k] + sm.avz[j] * sm.avz[k];
        float cv = 0.95f * dot / (fmaxf(d1, 1e-8f) * fmaxf(d2, 1e-8f));
        float sv = sqrtf(fmaxf(1.f - cv * cv, 0.f));
        float dm = 0.5f * (d1 + d2);
        float fc2 = 2.f * sm.afc[j] * sm.afc[k];
        float pe = fmaxf(-k2 * dm * dm + __log2f(fc2), -8.0e4f);  // clamp -inf
        float pd = 2.f * k2 * dm;
        float peA0 = pe - lca[0], peA1 = pe - lca[1];
        float peA2 = pe - lca[2], peA3 = pe - lca[3];
        float* dst = &sm.apart[w][triu_idx(sm.asp[j], sm.asp[k]) * 33];

        #pragma unroll
        for (int z = 0; z < 8; z++) {
            // cos(theta - s) = cv*cos(s) + sv*sin(s); sv = sin(theta) >= 0
            float cd = __builtin_fmaf(cv, czv[z], sv * szv[z]);
            float x = __builtin_fmaf(0.5f, cd, 0.5f);
            float f1;
            if (z32) { float x2 = x*x, x4 = x2*x2, x8 = x4*x4, x16 = x8*x8; f1 = x16*x16; }
            else     { f1 = __powf(x, zeta); }
            atomicAdd(dst +  0 + z, f1 * __builtin_amdgcn_exp2f(__builtin_fmaf(pd, shfa[0], peA0)));
            atomicAdd(dst +  8 + z, f1 * __builtin_amdgcn_exp2f(__builtin_fmaf(pd, shfa[1], peA1)));
            atomicAdd(dst + 16 + z, f1 * __builtin_amdgcn_exp2f(__builtin_fmaf(pd, shfa[2], peA2)));
            atomicAdd(dst + 24 + z, f1 * __builtin_amdgcn_exp2f(__builtin_fmaf(pd, shfa[3], peA3)));
        }
    }
    __syncthreads();

    // ---- reduce partials + writeback ----
    const size_t ob = (size_t)bid * AEVLEN;
    if (tid < 64) {
        float r = sm.rpart[0][tid] + sm.rpart[1][tid] + sm.rpart[2][tid] + sm.rpart[3][tid];
        stF(out, ob + tid, r);
    }
    {   // angular rows 0..7 (first 256 of 320 outputs)
        int row = tid >> 5, f = tid & 31;
        int s = row * 33 + f;
        float v = sm.apart[0][s] + sm.apart[1][s] + sm.apart[2][s] + sm.apart[3][s];
        stF(out, ob + RADLEN + row * 32 + f, v);
    }
    if (tid < 64) {  // rows 8..9
        int idx = 256 + tid;
        int row = idx >> 5, f = idx & 31;
        int s = row * 33 + f;
        float v = sm.apart[0][s] + sm.apart[1][s] + sm.apart[2][s] + sm.apart[3][s];
        stF(out, ob + RADLEN + row * 32 + f, v);
    }
}

__global__ __launch_bounds__(256) void aev_kernel(
    const void* coords, const void* etaR, const void* shfR, const void* etaA,
    const void* zeta, const void* shfA, const void* shfZ,
    const int* __restrict__ species, void* out)
{
    __shared__ Smem sm;
    // dtype probe: ShfR[0] read as f32 is 0.9 iff inputs are f32 (wave-uniform)
    const float probe = __uint_as_float(((const unsigned int*)shfR)[0]);
    if (probe > 0.85f && probe < 0.95f) {
        aev_body<float>(sm, (const float*)coords, (const float*)etaR,
                        (const float*)shfR, (const float*)etaA, (const float*)zeta,
                        (const float*)shfA, (const float*)shfZ, species, (float*)out);
    } else {
        aev_body<__hip_bfloat16>(sm, (const __hip_bfloat16*)coords,
                        (const __hip_bfloat16*)etaR, (const __hip_bfloat16*)shfR,
                        (const __hip_bfloat16*)etaA, (const __hip_bfloat16*)zeta,
                        (const __hip_bfloat16*)shfA, (const __hip_bfloat16*)shfZ,
                        species, (__hip_bfloat16*)out);
    }
}

extern "C" void kernel_launch(void* const* d_in, const int* in_sizes, int n_in,
                              void* d_out, int out_size, void* d_ws, size_t ws_size,
                              hipStream_t stream) {
    aev_kernel<<<dim3(32 * NA), dim3(256), 0, stream>>>(
        d_in[0], d_in[1], d_in[2], d_in[3], d_in[4], d_in[5], d_in[6],
        (const int*)d_in[7], d_out);
}

// Round 9
// 75.469 us; speedup vs baseline: 1.3385x; 1.3385x over previous
//
#include <hip/hip_runtime.h>
#include <hip/hip_bf16.h>

// AEV for M=32 molecules, A=48 atoms, S=4 species.
// Output [M, A, 384]: [0:64] radial = species*16+shfR; [64:384] angular =
// pair_species_idx*32 + shfA*8 + shfZ.
//
// One 256-thread (4-wave) block per (molecule, center); all 1536 blocks
// co-resident. Wave 0 builds cutoff-compacted neighbor lists (ballot+popc).
// Radial: folded single-exp2 per (neighbor, shell), strided across waves.
// Angular: pairs are staged once (float4{cv,sv,pd,pe}) and COUNTING-SORTED by
// species-pair row (10 bins; rank = atomicAdd during staging). Rows processed
// in an unrolled r=0..9 loop: accumulator index r>>1 is compile-time, the
// owning-parity mask is applied once per row (not per pair), and the two
// half-waves process two different pairs of the same row simultaneously
// (2-address LDS broadcast is conflict-free), reconciled by one
// __shfl_xor(...,32) per row. Inner iteration ~12 VALU + 2 ds_read for TWO
// pairs (vs ~33 VALU/pair in the unsorted broadcast version).
// Per-wave partial AEVs in LDS, tree-reduced after one final barrier.
//
// Dtype probed at runtime (ShfR[0] as f32 == 0.9 <=> f32 inputs; confirmed f32).

#define NA 48
#define RCR_F 5.2f
#define RCA_F 3.5f
#define PI_F 3.14159265358979f
#define LOG2E_F 1.44269504088896f
#define RADLEN 64
#define AEVLEN 384

struct Smem {
    float sx[NA], sy[NA], sz[NA];
    int   ssp[NA];
    float ra[NA]; unsigned rbu[NA];                                // radial folded
    float ad[NA], avx[NA], avy[NA], avz[NA], afc[NA]; int asp[NA]; // d<=RCA list
    int   nR, nAn;
    float4 pstage[256];    // staged pairs {cv, sv, pd, pe}
    int    sortidx[256];   // row-sorted pair indices (into pstage)
    int    bins[10], start[10];
    float rpart[4][64];    // per-wave radial partials
    float apart[4][320];   // per-wave angular partials
};

template <typename T> __device__ __forceinline__ float toF(const T* p, int i);
template <> __device__ __forceinline__ float toF<float>(const float* p, int i) { return p[i]; }
template <> __device__ __forceinline__ float toF<__hip_bfloat16>(const __hip_bfloat16* p, int i) { return __bfloat162float(p[i]); }

template <typename T> __device__ __forceinline__ void stF(T* p, size_t i, float v);
template <> __device__ __forceinline__ void stF<float>(float* p, size_t i, float v) { p[i] = v; }
template <> __device__ __forceinline__ void stF<__hip_bfloat16>(__hip_bfloat16* p, size_t i, float v) { p[i] = __float2bfloat16(v); }

__device__ __forceinline__ int triu_idx(int a, int b) {
    int lo = a < b ? a : b;
    int hi = a < b ? b : a;
    return lo * 4 - (lo * (lo - 1)) / 2 + (hi - lo);  // 4x4 upper-tri, 0..9
}

template <typename T>
__device__ void aev_body(Smem& sm,
    const T* __restrict__ coords, const T* __restrict__ etaR_p,
    const T* __restrict__ shfR_p, const T* __restrict__ etaA_p,
    const T* __restrict__ zeta_p, const T* __restrict__ shfA_p,
    const T* __restrict__ shfZ_p, const int* __restrict__ species,
    T* __restrict__ out)
{
    const int tid  = threadIdx.x;   // 0..255
    const int lane = tid & 63;
    const int w    = tid >> 6;      // wave id 0..3
    const int bid  = blockIdx.x;    // 0..1535
    const int m  = bid / NA;
    const int ci = bid % NA;

    const float etaR = toF(etaR_p, 0);
    const float etaA = toF(etaA_p, 0);
    const float zeta = toF(zeta_p, 0);
    const float kR   = etaR * LOG2E_F;
    const float k2   = etaA * LOG2E_F;

    if (tid < NA) {
        int g = m * NA + tid;
        sm.sx[tid]  = toF(coords, 3 * g + 0);
        sm.sy[tid]  = toF(coords, 3 * g + 1);
        sm.sz[tid]  = toF(coords, 3 * g + 2);
        sm.ssp[tid] = species[g];
    }
    __syncthreads();

    if (w == 0) {
        const float cx = sm.sx[ci], cy = sm.sy[ci], cz = sm.sz[ci];
        float dx = 0.f, dy = 0.f, dz = 0.f, d = 1e30f;
        if (lane < NA && lane != ci) {
            dx = sm.sx[lane] - cx; dy = sm.sy[lane] - cy; dz = sm.sz[lane] - cz;
            d = sqrtf(dx * dx + dy * dy + dz * dz);
        }
        unsigned long long mR = __ballot(d <= RCR_F);
        unsigned long long mA = __ballot(d <= RCA_F);
        unsigned long long lanebit = 1ull << lane;
        unsigned long long below = lanebit - 1ull;
        if (mR & lanebit) {
            int s = __popcll(mR & below);
            float fcR = 0.5f * __cosf(d * (PI_F / RCR_F)) + 0.5f;
            // 0.25*exp(-etaR*(d-s)^2)*fc = exp2(ra*s + rb - kR*s^2)
            float rb = fmaxf(__log2f(0.25f * fcR) - kR * d * d, -8.0e4f);
            sm.ra[s]  = 2.f * kR * d;
            sm.rbu[s] = (__float_as_uint(rb) & ~3u) | (unsigned)sm.ssp[lane];
        }
        if (mA & lanebit) {
            int s = __popcll(mA & below);
            sm.ad[s]  = d;
            sm.avx[s] = dx; sm.avy[s] = dy; sm.avz[s] = dz;
            sm.afc[s] = 0.5f * __cosf(d * (PI_F / RCA_F)) + 0.5f;
            sm.asp[s] = sm.ssp[lane];
        }
        if (lane == 0) { sm.nR = (int)__popcll(mR); sm.nAn = (int)__popcll(mA); }
    }
    __syncthreads();

    const int nR  = sm.nR;
    const int nAn = sm.nAn;

    const float myShfR = toF(shfR_p, lane & 15);
    const int   mySp   = lane >> 4;
    const float myRc   = kR * myShfR * myShfR;
    const bool  z32    = (zeta == 32.f);

    // ---- radial partial: wave w handles neighbors w, w+4, ... ----
    float racc = 0.f;
    for (int i = w; i < nR; i += 4) {
        unsigned ru = sm.rbu[i];
        float arg = __builtin_fmaf(sm.ra[i], myShfR, __uint_as_float(ru)) - myRc;
        float t = __builtin_amdgcn_exp2f(arg);
        racc += ((int)(ru & 3u) == mySp) ? t : 0.f;
    }
    sm.rpart[w][lane] = racc;

    // ---- angular: stage + counting-sort by row, then row-major broadcast ----
    const int myA  = (lane >> 3) & 3;
    const int myZ  = lane & 7;
    const int p0   = lane >> 5;
    const float myShfA = toF(shfA_p, myA);
    const float myShfZ = toF(shfZ_p, myZ);
    const float myCz = __cosf(myShfZ);
    const float mySz = __sinf(myShfZ);
    const float myLc = k2 * myShfA * myShfA;

    float accs[5] = {0.f, 0.f, 0.f, 0.f, 0.f};
    const int np = nAn * (nAn - 1) / 2;

    for (int c0 = 0; c0 < np; c0 += 256) {
        const int nc = (np - c0 < 256) ? (np - c0) : 256;
        if (tid < 10) sm.bins[tid] = 0;
        __syncthreads();

        int myrow = -1, myrank = 0;
        if (tid < nc) {
            int p = c0 + tid;
            // decode p -> (j,k), j<k: T(j) = j*(b-j)/2, b = 2n-1
            const int b = 2 * nAn - 1;
            float s = sqrtf((float)(b * b - 8 * p));
            int j = (int)(((float)b - s) * 0.5f);
            if ((j + 1) * (b - 1 - j) <= 2 * p) j++;
            if (j * (b - j) > 2 * p) j--;
            int k = p - ((j * (b - j)) >> 1) + j + 1;

            float d1 = sm.ad[j], d2 = sm.ad[k];
            float dot = sm.avx[j] * sm.avx[k] + sm.avy[j] * sm.avy[k] + sm.avz[j] * sm.avz[k];
            float cv = 0.95f * dot / (fmaxf(d1, 1e-8f) * fmaxf(d2, 1e-8f));
            float sv = sqrtf(fmaxf(1.f - cv * cv, 0.f));
            float dm = 0.5f * (d1 + d2);
            float fc2 = 2.f * sm.afc[j] * sm.afc[k];
            float pe = fmaxf(-k2 * dm * dm + __log2f(fc2), -8.0e4f);  // clamp -inf
            float pd = 2.f * k2 * dm;
            sm.pstage[tid] = make_float4(cv, sv, pd, pe);
            myrow = triu_idx(sm.asp[j], sm.asp[k]);
            myrank = atomicAdd(&sm.bins[myrow], 1);
        }
        __syncthreads();
        if (tid == 0) {
            int s = 0;
            #pragma unroll
            for (int r = 0; r < 10; r++) { sm.start[r] = s; s += sm.bins[r]; }
        }
        __syncthreads();
        if (myrow >= 0) sm.sortidx[sm.start[myrow] + myrank] = tid;
        __syncthreads();

        // process rows: all 64 lanes active (half-waves take 2 pairs/row/iter)
        #pragma unroll
        for (int r = 0; r < 10; r++) {
            const int st = sm.start[r], cn = sm.bins[r];
            const int half = p0 ^ (r & 1);   // 0 = owning parity for row r
            float tacc = 0.f;
            for (int o2 = 2 * w; o2 < cn; o2 += 8) {   // wave-uniform trip count
                int ord = o2 + half;
                bool valid = ord < cn;
                int q = sm.sortidx[st + (valid ? ord : o2)];
                float4 P = sm.pstage[q];
                // cos(theta-s) = cv*cos(s)+sv*sin(s); sv = sin(theta) >= 0
                float cd = __builtin_fmaf(P.x, myCz, P.y * mySz);
                float x = __builtin_fmaf(0.5f, cd, 0.5f);
                float f1;
                if (z32) { float x2 = x*x, x4 = x2*x2, x8 = x4*x4, x16 = x8*x8; f1 = x16*x16; }
                else     { f1 = __powf(x, zeta); }
                float term = f1 * __builtin_amdgcn_exp2f(
                                 __builtin_fmaf(P.z, myShfA, P.w - myLc));
                tacc += valid ? term : 0.f;
            }
            float other = __shfl_xor(tacc, 32);
            accs[r >> 1] += (half == 0) ? (tacc + other) : 0.f;
        }
        __syncthreads();   // WAR: next chunk overwrites pstage/sortidx/bins
    }

    // lane l's 5 slots: flat apart index (2u+p0)*32 + myA*8 + myZ = lane + 64u
    sm.apart[w][lane + 0]   = accs[0];
    sm.apart[w][lane + 64]  = accs[1];
    sm.apart[w][lane + 128] = accs[2];
    sm.apart[w][lane + 192] = accs[3];
    sm.apart[w][lane + 256] = accs[4];
    __syncthreads();

    // ---- reduce partials + writeback ----
    const size_t ob = (size_t)bid * AEVLEN;
    if (tid < 64) {
        float r = sm.rpart[0][tid] + sm.rpart[1][tid] + sm.rpart[2][tid] + sm.rpart[3][tid];
        stF(out, ob + tid, r);
    }
    {
        float v = sm.apart[0][tid] + sm.apart[1][tid] + sm.apart[2][tid] + sm.apart[3][tid];
        stF(out, ob + RADLEN + tid, v);
    }
    if (tid < 64) {
        int s = 256 + tid;
        float v = sm.apart[0][s] + sm.apart[1][s] + sm.apart[2][s] + sm.apart[3][s];
        stF(out, ob + RADLEN + s, v);
    }
}

__global__ __launch_bounds__(256) void aev_kernel(
    const void* coords, const void* etaR, const void* shfR, const void* etaA,
    const void* zeta, const void* shfA, const void* shfZ,
    const int* __restrict__ species, void* out)
{
    __shared__ Smem sm;
    // dtype probe: ShfR[0] read as f32 is 0.9 iff inputs are f32 (wave-uniform)
    const float probe = __uint_as_float(((const unsigned int*)shfR)[0]);
    if (probe > 0.85f && probe < 0.95f) {
        aev_body<float>(sm, (const float*)coords, (const float*)etaR,
                        (const float*)shfR, (const float*)etaA, (const float*)zeta,
                        (const float*)shfA, (const float*)shfZ, species, (float*)out);
    } else {
        aev_body<__hip_bfloat16>(sm, (const __hip_bfloat16*)coords,
                        (const __hip_bfloat16*)etaR, (const __hip_bfloat16*)shfR,
                        (const __hip_bfloat16*)etaA, (const __hip_bfloat16*)zeta,
                        (const __hip_bfloat16*)shfA, (const __hip_bfloat16*)shfZ,
                        species, (__hip_bfloat16*)out);
    }
}

extern "C" void kernel_launch(void* const* d_in, const int* in_sizes, int n_in,
                              void* d_out, int out_size, void* d_ws, size_t ws_size,
                              hipStream_t stream) {
    aev_kernel<<<dim3(32 * NA), dim3(256), 0, stream>>>(
        d_in[0], d_in[1], d_in[2], d_in[3], d_in[4], d_in[5], d_in[6],
        (const int*)d_in[7], d_out);
}